// Round 2
// baseline (1858.951 us; speedup 1.0000x reference)
//
#include <hip/hip_runtime.h>
#include <hip/hip_fp16.h>

// Sinkhorn OT: bs=64 chains, d1=d2=768, lam=0.01, 100 iters + final LSE.
// Round 2 design:
//  - fp16 K/KT (RNE, scaled by 2^14; offset folded into cK2/cKT2) => 4x the
//    mantissa margin of bf16 which straddled the threshold.
//  - 256 blocks: 32 groups x 8 blocks; each group owns 2 chains (C=2 shares
//    each K read across 2 matvecs => halves aggregate L2 traffic), each block
//    owns a 96-column slice (per-CU stream /8).
//  - cross-block exchange via relaxed AGENT-scope (sc1) loads/stores + a
//    monotonic per-group counter. No acquire/release fences => no L2
//    invalidate => K/KT stay L2-resident.
//  - 85KB LDS/block forces 1 block/CU => all 256 blocks resident (spin-safe)
//    without cooperative launch.

#define D        768
#define NSPLIT   8
#define COLS     96         // D / NSPLIT
#define QPT      12         // (D/8) quads / NSPLIT
#define NITERS   100
#define INV_LAM  100.0f
#define C14      9.70406052784f   // 14*ln2 (2^14 scale folded into offsets)
#define SCALE14  16384.0f
#define LOG768   6.64385618977f

// ---- agent-scope (device) relaxed atomics: per-inst sc1, no cache fences ----
__device__ __forceinline__ void st_agent(float* p, float v) {
    __hip_atomic_store(p, v, __ATOMIC_RELAXED, __HIP_MEMORY_SCOPE_AGENT);
}
__device__ __forceinline__ float ld_agent(const float* p) {
    return __hip_atomic_load((float*)p, __ATOMIC_RELAXED, __HIP_MEMORY_SCOPE_AGENT);
}
__device__ __forceinline__ int ld_flag(const int* p) {
    return __hip_atomic_load((int*)p, __ATOMIC_RELAXED, __HIP_MEMORY_SCOPE_AGENT);
}

// ---- block reductions over 768 threads (12 waves), float2 lanes ----
__device__ __forceinline__ float2 bmax2(float a, float b, float2* red, int tid) {
    #pragma unroll
    for (int o = 32; o; o >>= 1) { a = fmaxf(a, __shfl_xor(a, o)); b = fmaxf(b, __shfl_xor(b, o)); }
    __syncthreads();
    if ((tid & 63) == 0) red[tid >> 6] = make_float2(a, b);
    __syncthreads();
    float2 r = red[0];
    #pragma unroll
    for (int k = 1; k < 12; ++k) { r.x = fmaxf(r.x, red[k].x); r.y = fmaxf(r.y, red[k].y); }
    return r;
}
__device__ __forceinline__ float2 bsum2(float a, float b, float2* red, int tid) {
    #pragma unroll
    for (int o = 32; o; o >>= 1) { a += __shfl_xor(a, o); b += __shfl_xor(b, o); }
    __syncthreads();
    if ((tid & 63) == 0) red[tid >> 6] = make_float2(a, b);
    __syncthreads();
    float2 r = red[0];
    #pragma unroll
    for (int k = 1; k < 12; ++k) { r.x += red[k].x; r.y += red[k].y; }
    return r;
}

// ---- dual-chain matvec over a 96-column, full-768-row fp16 slice ----
// kp = Kq + w*D + j ; e*w = ((float4*)s_e) + 2*w. Thread covers quads w+8t.
__device__ __forceinline__ void mv2(const uint4* __restrict__ kp,
                                    const float4* __restrict__ e0w,
                                    const float4* __restrict__ e1w,
                                    float& o0, float& o1) {
    float a0 = 0.f, a1 = 0.f, b0 = 0.f, b1 = 0.f;
    #pragma unroll 4
    for (int t = 0; t < QPT; ++t) {
        uint4 kv = kp[0]; kp += 8 * D;
        float4 xa = e0w[0], ya = e0w[1], xb = e1w[0], yb = e1w[1];
        e0w += 16; e1w += 16;
        __half2 h;
        h = *(const __half2*)&kv.x; float g0 = __low2float(h), g1 = __high2float(h);
        h = *(const __half2*)&kv.y; float g2 = __low2float(h), g3 = __high2float(h);
        h = *(const __half2*)&kv.z; float g4 = __low2float(h), g5 = __high2float(h);
        h = *(const __half2*)&kv.w; float g6 = __low2float(h), g7 = __high2float(h);
        a0 = fmaf(g0, xa.x, a0); a1 = fmaf(g1, xa.y, a1);
        a0 = fmaf(g2, xa.z, a0); a1 = fmaf(g3, xa.w, a1);
        a0 = fmaf(g4, ya.x, a0); a1 = fmaf(g5, ya.y, a1);
        a0 = fmaf(g6, ya.z, a0); a1 = fmaf(g7, ya.w, a1);
        b0 = fmaf(g0, xb.x, b0); b1 = fmaf(g1, xb.y, b1);
        b0 = fmaf(g2, xb.z, b0); b1 = fmaf(g3, xb.w, b1);
        b0 = fmaf(g4, yb.x, b0); b1 = fmaf(g5, yb.y, b1);
        b0 = fmaf(g6, yb.z, b0); b1 = fmaf(g7, yb.w, b1);
    }
    o0 = a0 + a1; o1 = b0 + b1;
}

// ---- prep: fp16-packed K (col-offsets) ; 6144 threads: (column j, part w) ----
__global__ void prep_cols(const float* __restrict__ dist, uint4* __restrict__ Kq,
                          float* __restrict__ cK2, float* __restrict__ cF2,
                          int* __restrict__ cnt) {
    int T = blockIdx.x * blockDim.x + threadIdx.x;
    if (T < 32) cnt[T] = 0;                         // zero group counters
    int j = T >> 3, w = T & 7;
    float mc = 3.402823e38f, mf = -3.402823e38f;
    for (int i = 96 * w; i < 96 * w + 96; ++i) {
        float d = dist[(size_t)i * D + j];
        mc = fminf(mc, d);
        mf = fmaxf(mf, __logf(d) - d * INV_LAM);
    }
    #pragma unroll
    for (int o = 1; o < 8; o <<= 1) { mc = fminf(mc, __shfl_xor(mc, o)); mf = fmaxf(mf, __shfl_xor(mf, o)); }
    if (w == 0) { cK2[j] = -mc * INV_LAM - C14; cF2[j] = mf; }
    for (int t = 0; t < QPT; ++t) {
        int q = 12 * w + t;
        union { uint4 u4; __half2 h2[8]; } pk;
        #pragma unroll
        for (int r = 0; r < 4; ++r) {
            float d0 = dist[(size_t)(8 * q + 2 * r) * D + j];
            float d1 = dist[(size_t)(8 * q + 2 * r + 1) * D + j];
            __half lo = __float2half(__expf((mc - d0) * INV_LAM) * SCALE14);
            __half hi = __float2half(__expf((mc - d1) * INV_LAM) * SCALE14);
            pk.h2[r] = __halves2half2(lo, hi);
        }
        Kq[(size_t)q * D + j] = pk.u4;
    }
}

// ---- prep: fp16-packed K^T (row-offsets) ; (row i, part w) ----
__global__ void prep_rows(const float* __restrict__ dist, uint4* __restrict__ KTq,
                          float* __restrict__ cKT2) {
    int T = blockIdx.x * blockDim.x + threadIdx.x;
    int i = T >> 3, w = T & 7;
    const float* row = dist + (size_t)i * D;
    float mr = 3.402823e38f;
    for (int jj = 96 * w; jj < 96 * w + 96; ++jj) mr = fminf(mr, row[jj]);
    #pragma unroll
    for (int o = 1; o < 8; o <<= 1) mr = fminf(mr, __shfl_xor(mr, o));
    if (w == 0) cKT2[i] = -mr * INV_LAM - C14;
    for (int t = 0; t < QPT; ++t) {
        int q = 12 * w + t;
        union { uint4 u4; __half2 h2[8]; } pk;
        #pragma unroll
        for (int r = 0; r < 4; ++r) {
            float d0 = row[8 * q + 2 * r];
            float d1 = row[8 * q + 2 * r + 1];
            __half lo = __float2half(__expf((mr - d0) * INV_LAM) * SCALE14);
            __half hi = __float2half(__expf((mr - d1) * INV_LAM) * SCALE14);
            pk.h2[r] = __halves2half2(lo, hi);
        }
        KTq[(size_t)q * D + i] = pk.u4;
    }
}

// ---- main: 256 blocks = 32 groups x 8 parts, 2 chains per group ----
__global__ __launch_bounds__(768) void sink2(
    const float* __restrict__ mu, const float* __restrict__ nu,
    const float* __restrict__ dist,
    const uint4* __restrict__ Kq, const uint4* __restrict__ KTq,
    const float* __restrict__ cK2, const float* __restrict__ cKT2,
    const float* __restrict__ cF2,
    float* __restrict__ vbuf, float* __restrict__ ubuf,
    float* __restrict__ fbuf, int* __restrict__ cnt,
    float* __restrict__ out) {
    __shared__ __align__(16) float s_e0[D];
    __shared__ __align__(16) float s_e1[D];
    __shared__ float2 s_red[16];
    __shared__ char s_pad[78848];   // forces LDS>80KB => 1 block/CU => 256 blocks all resident
    if (mu == nullptr) { s_pad[threadIdx.x & 255] = 1; s_e0[0] = (float)s_pad[0]; }

    const int tid = threadIdx.x;
    const int B = blockIdx.x;
    const int x = B & 7, s = B >> 3;           // presumed XCD, slot (perf-only)
    const int G = x * 4 + (s >> 3);            // group id 0..31
    const int p = s & 7;                       // part 0..7 (column slice)
    const int c0 = 2 * G, c1 = 2 * G + 1;      // chains of this group
    const int jj = tid >> 3, w = tid & 7;
    const int j = p * COLS + jj;

    const float r_lnu0 = __logf(nu[(size_t)c0 * D + j]);
    const float r_lnu1 = __logf(nu[(size_t)c1 * D + j]);
    const float r_lmu0 = __logf(mu[(size_t)c0 * D + j]);
    const float r_lmu1 = __logf(mu[(size_t)c1 * D + j]);
    const float r_cK2 = cK2[j], r_cKT2 = cKT2[j], r_cF = cF2[j];

    const uint4* kp0 = Kq + (size_t)w * D + j;
    const uint4* ktp0 = KTq + (size_t)w * D + j;
    const float4* e0b = (const float4*)s_e0 + 2 * w;
    const float4* e1b = (const float4*)s_e1 + 2 * w;

    s_e0[tid] = 1.f; s_e1[tid] = 1.f;          // e_u init: exp(lu0 - cu0) = 1
    float coff0 = -LOG768, coff1 = -LOG768;
    float lv0 = 0.f, lv1 = 0.f;
    int hs = 0;
    __syncthreads();

    for (int it = 0; it < NITERS; ++it) {
        // ---------- v-step ----------
        float S0, S1;
        mv2(kp0, e0b, e1b, S0, S1);
        #pragma unroll
        for (int o = 1; o < 8; o <<= 1) { S0 += __shfl_xor(S0, o); S1 += __shfl_xor(S1, o); }
        if (w == 0) {
            lv0 = r_lnu0 - (__logf(S0) + r_cK2 + coff0);
            lv1 = r_lnu1 - (__logf(S1) + r_cK2 + coff1);
            st_agent(&vbuf[(size_t)c0 * D + j], lv0);
            st_agent(&vbuf[(size_t)c1 * D + j], lv1);
        }
        // exchange lv -> e_v
        asm volatile("s_waitcnt vmcnt(0)" ::: "memory");
        __syncthreads();
        if (tid == 0) {
            __hip_atomic_fetch_add(&cnt[G], 1, __ATOMIC_RELAXED, __HIP_MEMORY_SCOPE_AGENT);
            const int target = NSPLIT * (hs + 1);
            while (ld_flag(&cnt[G]) < target) __builtin_amdgcn_s_sleep(2);
        }
        __syncthreads();
        __atomic_signal_fence(__ATOMIC_ACQUIRE);
        {
            float x0 = ld_agent(&vbuf[(size_t)c0 * D + tid]);
            float x1 = ld_agent(&vbuf[(size_t)c1 * D + tid]);
            float2 cv = bmax2(x0, x1, s_red, tid);
            s_e0[tid] = __expf(x0 - cv.x);
            s_e1[tid] = __expf(x1 - cv.y);
            coff0 = cv.x; coff1 = cv.y;
        }
        ++hs;
        __syncthreads();

        // ---------- u-step ----------
        float T0, T1;
        mv2(ktp0, e0b, e1b, T0, T1);
        #pragma unroll
        for (int o = 1; o < 8; o <<= 1) { T0 += __shfl_xor(T0, o); T1 += __shfl_xor(T1, o); }
        if (w == 0) {
            float lu0 = r_lmu0 - (__logf(T0) + r_cKT2 + coff0);
            float lu1 = r_lmu1 - (__logf(T1) + r_cKT2 + coff1);
            st_agent(&ubuf[(size_t)c0 * D + j], lu0);
            st_agent(&ubuf[(size_t)c1 * D + j], lu1);
        }
        // exchange lu -> e_u
        asm volatile("s_waitcnt vmcnt(0)" ::: "memory");
        __syncthreads();
        if (tid == 0) {
            __hip_atomic_fetch_add(&cnt[G], 1, __ATOMIC_RELAXED, __HIP_MEMORY_SCOPE_AGENT);
            const int target = NSPLIT * (hs + 1);
            while (ld_flag(&cnt[G]) < target) __builtin_amdgcn_s_sleep(2);
        }
        __syncthreads();
        __atomic_signal_fence(__ATOMIC_ACQUIRE);
        {
            float x0 = ld_agent(&ubuf[(size_t)c0 * D + tid]);
            float x1 = ld_agent(&ubuf[(size_t)c1 * D + tid]);
            float2 cv = bmax2(x0, x1, s_red, tid);
            s_e0[tid] = __expf(x0 - cv.x);
            s_e1[tid] = __expf(x1 - cv.y);
            coff0 = cv.x; coff1 = cv.y;
        }
        ++hs;
        __syncthreads();
    }

    // ---------- final: -s[j] = lv[j] + log(SF[j]) + cF_j + cu ----------
    float F0 = 0.f, F1 = 0.f;
    #pragma unroll 2
    for (int t = 0; t < QPT; ++t) {
        int q = w + 8 * t;
        const float* dpp = dist + (size_t)(8 * q) * D + j;
        #pragma unroll
        for (int r = 0; r < 8; ++r) {
            float d = dpp[(size_t)r * D];
            float fv = __expf(__logf(d) - d * INV_LAM - r_cF);
            F0 = fmaf(fv, s_e0[8 * q + r], F0);
            F1 = fmaf(fv, s_e1[8 * q + r], F1);
        }
    }
    #pragma unroll
    for (int o = 1; o < 8; o <<= 1) { F0 += __shfl_xor(F0, o); F1 += __shfl_xor(F1, o); }
    float negs0 = 0.f, negs1 = 0.f;
    if (w == 0) {
        negs0 = lv0 + __logf(F0) + r_cF + coff0;
        negs1 = lv1 + __logf(F1) + r_cF + coff1;
    }
    float xm0 = (w == 0) ? negs0 : -3.402823e38f;
    float xm1 = (w == 0) ? negs1 : -3.402823e38f;
    float2 mm = bmax2(xm0, xm1, s_red, tid);
    float ez0 = 0.f, ez1 = 0.f;
    if (w == 0) { ez0 = __expf(negs0 - mm.x); ez1 = __expf(negs1 - mm.y); }
    float2 zz = bsum2(ez0, ez1, s_red, tid);

    if (tid == 0) {
        float* fb = fbuf + (size_t)(G * NSPLIT + p) * 4;
        st_agent(fb + 0, mm.x); st_agent(fb + 1, zz.x);
        st_agent(fb + 2, mm.y); st_agent(fb + 3, zz.y);
        asm volatile("s_waitcnt vmcnt(0)" ::: "memory");
        __hip_atomic_fetch_add(&cnt[G], 1, __ATOMIC_RELAXED, __HIP_MEMORY_SCOPE_AGENT);
        if (p == 0) {
            const int target = NSPLIT * (2 * NITERS + 1);
            while (ld_flag(&cnt[G]) < target) __builtin_amdgcn_s_sleep(2);
            __atomic_signal_fence(__ATOMIC_ACQUIRE);
            float pm0[8], pz0[8], pm1[8], pz1[8];
            #pragma unroll
            for (int pp = 0; pp < 8; ++pp) {
                const float* f2 = fbuf + (size_t)(G * NSPLIT + pp) * 4;
                pm0[pp] = ld_agent(f2 + 0); pz0[pp] = ld_agent(f2 + 1);
                pm1[pp] = ld_agent(f2 + 2); pz1[pp] = ld_agent(f2 + 3);
            }
            float m0 = pm0[0], m1 = pm1[0];
            #pragma unroll
            for (int pp = 1; pp < 8; ++pp) { m0 = fmaxf(m0, pm0[pp]); m1 = fmaxf(m1, pm1[pp]); }
            float z0 = 0.f, z1 = 0.f;
            #pragma unroll
            for (int pp = 0; pp < 8; ++pp) {
                z0 += pz0[pp] * __expf(pm0[pp] - m0);
                z1 += pz1[pp] * __expf(pm1[pp] - m1);
            }
            out[c0] = __expf(m0) * z0;
            out[c1] = __expf(m1) * z1;
        }
    }
}

extern "C" void kernel_launch(void* const* d_in, const int* in_sizes, int n_in,
                              void* d_out, int out_size, void* d_ws, size_t ws_size,
                              hipStream_t stream) {
    const float* mu   = (const float*)d_in[0];
    const float* nu   = (const float*)d_in[1];
    const float* dist = (const float*)d_in[2];
    float* out = (float*)d_out;
    (void)in_sizes; (void)n_in; (void)out_size; (void)ws_size;

    char* w8 = (char*)d_ws;                      // ~2.77 MB total
    uint4* Kq   = (uint4*)(w8);                  // 1,179,648 B
    uint4* KTq  = (uint4*)(w8 + 1179648);        // 1,179,648 B
    float* cK2  = (float*)(w8 + 2359296);        // 3072 B
    float* cKT2 = (float*)(w8 + 2362368);        // 3072 B
    float* cF2  = (float*)(w8 + 2365440);        // 3072 B
    float* vbuf = (float*)(w8 + 2368512);        // 196,608 B
    float* ubuf = (float*)(w8 + 2565120);        // 196,608 B
    float* fbuf = (float*)(w8 + 2761728);        // 4096 B
    int*   cnt  = (int*)(w8 + 2765824);          // 128 B

    prep_cols<<<24, 256, 0, stream>>>(dist, Kq, cK2, cF2, cnt);
    prep_rows<<<24, 256, 0, stream>>>(dist, KTq, cKT2);
    sink2<<<256, 768, 0, stream>>>(mu, nu, dist, Kq, KTq, cK2, cKT2, cF2,
                                   vbuf, ubuf, fbuf, cnt, out);
}